// Round 10
// baseline (117.959 us; speedup 1.0000x reference)
//
#include <hip/hip_runtime.h>

// SSIM, N=32 images 512x512 fp32, 11x11 Gaussian (separable via rank-1
// window), zero pad, scalar mean output.
//
// R10: halo-work cut + single-round grid on the proven R9 body.
// Evidence R5/R7/R8/R9: wall ~= 2.4 x per-SIMD VALU-busy regardless of
// barriers (R9), wave supply (R7), prefetch (R7); only instruction-count
// cuts moved wall (R8). So: RROWS 32->64:
//  - halo factor ITERS/RROWS = 74/64 = 1.156 vs 42/32 = 1.31 -> -12% work
//  - grid (8,32) = 256 blocks = exactly 1 block/CU: one dispatch round,
//    no second-round tail; 4 waves/CU = 1/SIMD (4 indep accumulator
//    chains give enough single-wave ILP to keep the SIMD fed).
// Body unchanged from R9 (verified absmax 0): 11-row chunk staging
// (46.6KB LDS), 2 barriers/chunk, all 22 next-chunk loads issued at
// compute start, packed fp32 (v_pk_*) on (s,d)=(x+y,x-y), M=2 cols/thread,
// zero column halo via per-row edge zeros, 11x-unrolled static mod-11
// vertical register ring. No min-waves launch_bounds (R3 spill lesson).

typedef float v2f __attribute__((ext_vector_type(2)));
typedef float v4f __attribute__((ext_vector_type(4)));

#define IMG_H 512
#define IMG_W 512
#define NIMG  32
#define NT    256
#define RROWS 64
#define ITERS (RROWS + 10)   // 74 input rows streamed
#define CH    11             // chunk rows == ring modulus
#define NCHNK 7              // ceil(74/11)
// LDS row: idx 0 pad | 1..5 zeroL | 6..517 data (col c -> idx 6+c) |
//          518..522 zeroR | 523 pad
#define LDSW  524

#define C1F  1.0e-4f
#define C2F  9.0e-4f
#define EPSF 1.0e-8f

static __device__ __forceinline__ v2f pkfma(float s, v2f a, v2f b) {
    v2f sv = {s, s};
    return __builtin_elementwise_fma(sv, a, b);   // -> v_pk_fma_f32
}

__global__ __launch_bounds__(NT) void ssim_kernel(
    const float* __restrict__ xg, const float* __restrict__ yg,
    const float* __restrict__ wg, float* __restrict__ out)
{
    const int t    = threadIdx.x;       // 0..255
    const int lane = t & 63;
    const int chnk = blockIdx.x;        // 0..7
    const int img  = blockIdx.y;        // 0..31
    const int r0   = chnk * RROWS;
    const int c0   = 2 * t;             // own columns c0, c0+1

    const float* xb = xg + (size_t)img * (IMG_H * IMG_W);
    const float* yb = yg + (size_t)img * (IMG_H * IMG_W);

    __shared__ alignas(16) v2f ssd[CH][LDSW];   // 11-row (s,d) buffer, 46KB
    __shared__ float wredS[4];

    // 1D taps = row sums of normalized 2D window -> SGPRs via readfirstlane.
    float rs = 0.f;
    if (lane < 11) {
        #pragma unroll
        for (int j = 0; j < 11; ++j) rs += wg[lane * 11 + j];
    }
    float g[11];
    #pragma unroll
    for (int k = 0; k < 11; ++k) {
        int gi = __shfl(__float_as_int(rs), k, 64);
        g[k] = __int_as_float(__builtin_amdgcn_readfirstlane(gi));
    }

    const v2f z2 = {0.f, 0.f};

    // per-row static edge zeros (image boundary), written once; data writes
    // never touch idx 1..5 / 518..522. Visible after first barrier.
    if (t < 55)               { ssd[t / 5][1 + t % 5] = z2; }
    if (t >= 128 && t < 183)  { const int u = t - 128; ssd[u / 5][518 + u % 5] = z2; }

    // pending next-chunk loads (registers): 11 rows x (x,y) float2 = 44 VGPR
    v2f px[CH], py[CH];
    #pragma unroll
    for (int m = 0; m < CH; ++m) {
        const int r = r0 - 5 + m;
        if ((unsigned)r < IMG_H) {
            px[m] = *(const v2f*)(xb + (size_t)r * IMG_W + c0);
            py[m] = *(const v2f*)(yb + (size_t)r * IMG_W + c0);
        } else { px[m] = z2; py[m] = z2; }
    }

    // vertical register rings: (s,d),(s2,d2) x 2 cols x 11 rows = 88 floats
    v2f rSD[CH][2], rQ[CH][2];

    float acc = 0.f;

    #pragma unroll 1
    for (int c = 0; c < NCHNK; ++c) {
        // ---- write phase: convert pending rows to (s,d), stage to LDS ----
        #pragma unroll
        for (int m = 0; m < CH; ++m) {
            const v2f sv = px[m] + py[m];       // v_pk_add_f32
            const v2f dv = px[m] - py[m];
            v4f st = {sv.x, dv.x, sv.y, dv.y};
            *(v4f*)&ssd[m][6 + c0] = st;
        }
        __syncthreads();

        // ---- issue ALL next-chunk loads (consumed after next barrier) ----
        if (c < NCHNK - 1) {
            #pragma unroll
            for (int m = 0; m < CH; ++m) {
                const int r = r0 + 6 + CH * c + m;
                if ((unsigned)r < IMG_H) {
                    px[m] = *(const v2f*)(xb + (size_t)r * IMG_W + c0);
                    py[m] = *(const v2f*)(yb + (size_t)r * IMG_W + c0);
                } else { px[m] = z2; py[m] = z2; }
            }
        }

        // ---- compute phase: 11 row-iterations from LDS ----
        #pragma unroll
        for (int s = 0; s < CH; ++s) {
            const int i = CH * c + s;
            if (i < ITERS) {                    // uniform tail guard
                // horizontal conv, both cols; window element j (0..13) at
                // LDS idx c0+j (col c0-6+j); 7 b128 reads, squares once.
                v2f hA = z2, hB = z2, qA = z2, qB = z2;
                #pragma unroll
                for (int m = 0; m < 7; ++m) {
                    const v4f w4 = *(const v4f*)&ssd[s][c0 + 2 * m];
                    const v2f e0 = {w4.x, w4.y};   // j = 2m
                    const v2f e1 = {w4.z, w4.w};   // j = 2m+1
                    {
                        const int j = 2 * m;
                        if (j >= 1) {
                            const v2f f0 = e0 * e0;          // v_pk_mul_f32
                            if (j <= 11) {
                                hA = pkfma(g[j - 1], e0, hA);
                                qA = pkfma(g[j - 1], f0, qA);
                            }
                            if (j >= 2) {
                                hB = pkfma(g[j - 2], e0, hB);
                                qB = pkfma(g[j - 2], f0, qB);
                            }
                        }
                    }
                    {
                        const int j = 2 * m + 1;
                        if (j <= 12) {
                            const v2f f1 = e1 * e1;
                            if (j <= 11) {
                                hA = pkfma(g[j - 1], e1, hA);
                                qA = pkfma(g[j - 1], f1, qA);
                            }
                            if (j >= 2) {
                                hB = pkfma(g[j - 2], e1, hB);
                                qB = pkfma(g[j - 2], f1, qB);
                            }
                        }
                    }
                }
                rSD[s][0] = hA; rSD[s][1] = hB;
                rQ[s][0]  = qA; rQ[s][1]  = qB;

                if (i >= 10) {                  // output row r0 + i - 10
                    #pragma unroll
                    for (int cc = 0; cc < 2; ++cc) {
                        v2f mSD = z2, mQ = z2;
                        #pragma unroll
                        for (int j = 0; j < 11; ++j) {
                            const int sl = (s + 1 + j) % 11;   // static
                            mSD = pkfma(g[j], rSD[sl][cc], mSD);
                            mQ  = pkfma(g[j], rQ[sl][cc],  mQ);
                        }
                        const v2f t2 = mSD * mSD;      // (mS^2, mD^2)
                        const float a    = 0.5f  * (t2.x + t2.y); // mx2+my2
                        const float muxy = 0.25f * (t2.x - t2.y); // mx*my
                        const float ep   = 0.5f  * (mQ.x + mQ.y); // Ex2+Ey2
                        const float eq   = 0.25f * (mQ.x - mQ.y); // Exy
                        const float sxy  = eq - muxy;
                        const float ssum = ep - a;
                        const float num  = fmaf(2.f, muxy, C1F) * fmaf(2.f, sxy, C2F);
                        const float den  = (a + C1F) * (ssum + C2F);
                        float v = num * __builtin_amdgcn_rcpf(den + EPSF);
                        acc += fminf(fmaxf(v, 0.f), 1.f);
                    }
                }
            }
        }
        __syncthreads();   // protect buffer from next chunk's writes
    }

    // block reduction: wave shuffle, 4 slots in LDS, one atomic per block
    #pragma unroll
    for (int off = 32; off > 0; off >>= 1)
        acc += __shfl_down(acc, off, 64);
    if (lane == 0) wredS[t >> 6] = acc;
    __syncthreads();
    if (t == 0) {
        const float tot = (wredS[0] + wredS[1]) + (wredS[2] + wredS[3]);
        atomicAdd(out, tot * (1.0f / (float)((size_t)NIMG * IMG_H * IMG_W)));
    }
}

extern "C" void kernel_launch(void* const* d_in, const int* in_sizes, int n_in,
                              void* d_out, int out_size, void* d_ws, size_t ws_size,
                              hipStream_t stream) {
    const float* x = (const float*)d_in[0];
    const float* y = (const float*)d_in[1];
    const float* w = (const float*)d_in[2];
    float* out = (float*)d_out;

    // d_out is re-poisoned to 0xAA before every timed launch; zero it first.
    hipMemsetAsync(out, 0, sizeof(float), stream);

    dim3 grid(IMG_H / RROWS, NIMG);    // (8, 32) = 256 blocks = 1/CU
    ssim_kernel<<<grid, dim3(NT), 0, stream>>>(x, y, w, out);
}